// Round 8
// baseline (296.979 us; speedup 1.0000x reference)
//
#include <hip/hip_runtime.h>
#include <stdint.h>

typedef unsigned short u16;
typedef __bf16 bfx8 __attribute__((ext_vector_type(8)));
typedef float f32x4 __attribute__((ext_vector_type(4)));

#define HD 768
#define NTREE 40000
#define NCODES 10000
#define GNN 1536
#define OUTD 512
#define NBV 512
#define VNEG (-1e30f)
#define TB 8

// GEMM: 256x256 tile, BK=64, 8 waves (2x4 of 64x32 per quadrant),
// phase = one 128x128 C-quadrant x K=64; 1 half-tile staged per phase;
// counted WAITV before phase barriers; NO manual lgkm/sched_barrier --
// compiler emits fine-grained lgkmcnt so ds_read burst overlaps MFMA.
#define BM 256
#define BN 256
#define BK 64
#define NKT (HD / BK)                // 12
#define NMT ((NTREE + BM - 1) / BM)  // 157
#define NNT (GNN / BN)               // 6
#define GRID (NMT * NNT)             // 942
#define Q8 (GRID / 8)                // 117
#define R8 (GRID % 8)                // 6

#define WAITV(n) asm volatile("s_waitcnt vmcnt(" #n ")" ::: "memory")

__device__ __forceinline__ float bf2f(u16 u) {
  union { uint32_t i; float f; } v; v.i = ((uint32_t)u) << 16; return v.f;
}
__device__ __forceinline__ u16 f2bf(float f) {
  union { float fl; uint32_t i; } v; v.fl = f;
  uint32_t u = v.i;
  u += 0x7FFFu + ((u >> 16) & 1u);
  return (u16)(u >> 16);
}

// ---------------- K0: fused convE (fp32->bf16) + Bt build -----------------
#define NBLK_CONV 30000  // NTREE*HD/4/256
__global__ void k_prep(const float* __restrict__ E, u16* __restrict__ Ebf,
                       const float* __restrict__ w1, u16* __restrict__ Bt) {
  const int bid = blockIdx.x, tid = threadIdx.x;
  if (bid < NBLK_CONV) {
    const int i = bid * 256 + tid;
    float4 v = ((const float4*)E)[i];
    ushort4 r;
    r.x = f2bf(v.x); r.y = f2bf(v.y); r.z = f2bf(v.z); r.w = f2bf(v.w);
    ((ushort4*)Ebf)[i] = r;
  } else {
    const int idx = (bid - NBLK_CONV) * 256 + tid;
    if (idx < GNN * HD) {
      const int n = idx / HD, k = idx % HD;
      const int srow = k + ((n >= HD) ? HD : 0);
      const int scol = (n >= HD) ? (n - HD) : n;
      Bt[idx] = f2bf(w1[(size_t)srow * HD + scol]);
    }
  }
}

// ---------------- K1: bf16 MFMA GEMM  PQ[40000][1536] = Ebf @ B -----------
// LDS: A buf c at u16 c*16384 (32KB); B buf c at 32768 + c*16384. 128KB.
// Row r at r*128B; 16B chunk phys = logical ^ (r&7) (both-sides swizzle).
__global__ __launch_bounds__(512, 2) void k_gemm(const u16* __restrict__ A,
                                                 const u16* __restrict__ B,
                                                 u16* __restrict__ C) {
  __shared__ u16 lds[65536];  // 128 KB

  const int tid    = threadIdx.x;
  const int lane   = tid & 63;
  const int wv     = tid >> 6;       // 0..7
  const int wr     = wv >> 2;        // 0..1: 64-row slice within quadrant
  const int wc     = wv & 3;         // 0..3: 32-col slice within quadrant
  const int lane15 = lane & 15;
  const int g      = lane >> 4;      // 0..3: 16B k-chunk within K=32 step

  // bijective XCD swizzle, nt-minor (blocks on one XCD share the A panel)
  const int orig = blockIdx.x;
  const int xcd = orig & 7, lin = orig >> 3;
  const int wg = (xcd < R8 ? xcd * (Q8 + 1) : R8 * (Q8 + 1) + (xcd - R8) * Q8) + lin;
  const int mt = wg / NNT, nt = wg % NNT;
  const int tm = mt * BM, tn = nt * BN;

  // staging source offsets (u16 elems; inverse-swizzled global source)
  uint32_t aOff[2][2], bOff[2][2];  // [u][half]
#pragma unroll
  for (int u = 0; u < 2; ++u) {
    const int o    = u * 8192 + tid * 16;          // byte in 16KB half
    const int rloc = o >> 7;                        // local row 0..127
    const int c    = ((o >> 4) & 7) ^ (rloc & 7);   // logical 16B chunk
#pragma unroll
    for (int h = 0; h < 2; ++h) {
      int ra = tm + h * 128 + rloc; if (ra > NTREE - 1) ra = NTREE - 1;
      aOff[u][h] = (uint32_t)ra * HD + c * 8;
      bOff[u][h] = (uint32_t)(tn + h * 128 + rloc) * HD + c * 8;
    }
  }

#define STAGE_A(MH, NB, TT) do {                                               \
    _Pragma("unroll") for (int u = 0; u < 2; ++u)                              \
      __builtin_amdgcn_global_load_lds(                                        \
        (const __attribute__((address_space(1))) void*)(A + aOff[u][MH] + (TT) * BK), \
        (__attribute__((address_space(3))) void*)((char*)lds + (NB) * 32768 +  \
            (MH) * 16384 + u * 8192 + tid * 16),                               \
        16, 0, 0);                                                             \
  } while (0)

#define STAGE_B(NH, NB, TT) do {                                               \
    _Pragma("unroll") for (int u = 0; u < 2; ++u)                              \
      __builtin_amdgcn_global_load_lds(                                        \
        (const __attribute__((address_space(1))) void*)(B + bOff[u][NH] + (TT) * BK), \
        (__attribute__((address_space(3))) void*)((char*)lds + 65536 +         \
            (NB) * 32768 + (NH) * 16384 + u * 8192 + tid * 16),                \
        16, 0, 0);                                                             \
  } while (0)

  f32x4 acc[4][4][2];  // [quadrant][mf][nf]
#pragma unroll
  for (int q = 0; q < 4; ++q)
#pragma unroll
    for (int i = 0; i < 4; ++i)
#pragma unroll
      for (int j = 0; j < 2; ++j) acc[q][i][j] = (f32x4){0.f, 0.f, 0.f, 0.f};

  int colz[2];
  colz[0] = ((0 * 4 + g) ^ (lane15 & 7)) * 8;
  colz[1] = ((1 * 4 + g) ^ (lane15 & 7)) * 8;
  const int aLane = wr * 4096 + lane15 * 64;  // u16; + Mh*8192 + mf*1024
  const int bLane = wc * 2048 + lane15 * 64;  // u16; + Nh*8192 + nf*1024

  bfx8 aF[4][2];        // current M-half A frags (overwritten at ph3)
  bfx8 bN0[2][2];       // B(N0) frags, live whole tile
  bfx8 bN1[2][2];       // B(N1) frags, live whole tile

#define READ_A(MH, BA) do {                                                    \
    _Pragma("unroll") for (int mf = 0; mf < 4; ++mf)                           \
      _Pragma("unroll") for (int ks = 0; ks < 2; ++ks)                         \
        aF[mf][ks] = *(const bfx8*)&lds[(BA) + (MH) * 8192 + aLane +           \
                                        mf * 1024 + colz[ks]];                 \
  } while (0)

#define READ_B(DST, NH, BB) do {                                               \
    _Pragma("unroll") for (int nf = 0; nf < 2; ++nf)                           \
      _Pragma("unroll") for (int ks = 0; ks < 2; ++ks)                         \
        DST[nf][ks] = *(const bfx8*)&lds[(BB) + (NH) * 8192 + bLane +          \
                                         nf * 1024 + colz[ks]];                \
  } while (0)

#define MFMA_Q(Q, BFR) do {                                                    \
    __builtin_amdgcn_s_setprio(1);                                             \
    _Pragma("unroll") for (int mf = 0; mf < 4; ++mf)                           \
      _Pragma("unroll") for (int nf = 0; nf < 2; ++nf)                         \
        _Pragma("unroll") for (int ks = 0; ks < 2; ++ks)                       \
          acc[Q][mf][nf] = __builtin_amdgcn_mfma_f32_16x16x32_bf16(            \
              aF[mf][ks], BFR[nf][ks], acc[Q][mf][nf], 0, 0, 0);               \
    __builtin_amdgcn_s_setprio(0);                                             \
  } while (0)

  // prologue: stage tile0 halves A0,B0,B1,A1; drain A0,B0; barrier
  STAGE_A(0, 0, 0);
  STAGE_B(0, 0, 0);
  STAGE_B(1, 0, 0);
  STAGE_A(1, 0, 0);
  WAITV(4);
  __builtin_amdgcn_s_barrier();

  for (int t = 0; t < NKT; ++t) {
    const int bA = (t & 1) * 16384;
    const int bB = 32768 + (t & 1) * 16384;
    const int nb = (t + 1) & 1;
    const bool more = (t + 1 < NKT);

    // ph1: q0=(M0,N0). reads A(M0)=8 + B(N0)=4. stage A0(t+1). drain B1(t).
    READ_A(0, bA);
    READ_B(bN0, 0, bB);
    if (more) STAGE_A(0, nb, t + 1);
    __builtin_amdgcn_s_barrier();
    MFMA_Q(0, bN0);
    if (more) { WAITV(4); } else { WAITV(2); }
    __builtin_amdgcn_s_barrier();

    // ph2: q1=(M0,N1). reads B(N1)=4. stage B0(t+1). drain A1(t).
    READ_B(bN1, 1, bB);
    if (more) STAGE_B(0, nb, t + 1);
    __builtin_amdgcn_s_barrier();
    MFMA_Q(1, bN1);
    if (more) { WAITV(4); } else { WAITV(0); }
    __builtin_amdgcn_s_barrier();

    // ph3: q2=(M1,N1). reads A(M1)=8. stage B1(t+1). no drain.
    READ_A(1, bA);
    if (more) STAGE_B(1, nb, t + 1);
    __builtin_amdgcn_s_barrier();
    MFMA_Q(2, bN1);
    __builtin_amdgcn_s_barrier();

    // ph4: q3=(M1,N0). reads NOTHING (bN0 still live). stage A1(t+1).
    // drain A0,B0(t+1) for ph1(t+1).
    if (more) STAGE_A(1, nb, t + 1);
    __builtin_amdgcn_s_barrier();
    MFMA_Q(3, bN0);
    if (more) { WAITV(4); }
    __builtin_amdgcn_s_barrier();
  }

  // epilogue: q -> (Mh,Nh): 0->(0,0) 1->(0,1) 2->(1,1) 3->(1,0)
  const int r0 = (lane >> 4) * 4, cc = lane15;
  const int qmh[4] = {0, 0, 1, 1}, qnh[4] = {0, 1, 1, 0};
#pragma unroll
  for (int q = 0; q < 4; ++q) {
#pragma unroll
    for (int mf = 0; mf < 4; ++mf) {
#pragma unroll
      for (int nf = 0; nf < 2; ++nf) {
#pragma unroll
        for (int rr = 0; rr < 4; ++rr) {
          const int row = tm + qmh[q] * 128 + wr * 64 + mf * 16 + r0 + rr;
          if (row < NTREE) {
            const int col = tn + qnh[q] * 128 + wc * 32 + nf * 16 + cc;
            C[(size_t)row * GNN + col] = f2bf(acc[q][mf][nf][rr]);
          }
        }
      }
    }
  }
#undef MFMA_Q
#undef READ_A
#undef READ_B
#undef STAGE_A
#undef STAGE_B
}

// ---------------- K2: scores + masked softmax + dag_emb (bf16 out) --------
__global__ __launch_bounds__(512) void k_attn(const u16* __restrict__ PQ,
                                              const u16* __restrict__ Ebf,
                                              const float* __restrict__ b1,
                                              const float* __restrict__ w2,
                                              const float* __restrict__ b2,
                                              const float* __restrict__ masks,
                                              const int* __restrict__ leaves,
                                              const int* __restrict__ anc,
                                              u16* __restrict__ dag) {
  const int n = blockIdx.x;
  const int tid = threadIdx.x, lane = tid & 63, wv = tid >> 6;
  __shared__ float sc[8];
  __shared__ float m_s[8];
  __shared__ int   an_s[8];
  __shared__ int   lv_s[8];
  if (tid < 8) {
    an_s[tid] = anc[n * 8 + tid];
    lv_s[tid] = leaves[n * 8 + tid];
    m_s[tid]  = masks[n * 8 + tid];
  }
  __syncthreads();

  {
    const int a = wv;
    const float mm = m_s[a];
    if (mm == 0.f) {
      if (lane == 0) sc[a] = VNEG;
    } else {
      const int l = lv_s[a], an = an_s[a];
      const u16* pr = PQ + (size_t)l * GNN;
      const u16* qr = PQ + (size_t)an * GNN + HD;
      const int d0 = lane * 12;
      float s = 0.f;
#pragma unroll
      for (int jj = 0; jj < 3; ++jj) {
        const int d = d0 + jj * 4;
        ushort4 pv = *(const ushort4*)(pr + d);
        ushort4 qv = *(const ushort4*)(qr + d);
        float4  bb = *(const float4*)(b1 + d);
        float4  ww = *(const float4*)(w2 + d);
        float v;
        v = fmaxf(bf2f(pv.x) + bf2f(qv.x) + bb.x, 0.f); s += v * ww.x;
        v = fmaxf(bf2f(pv.y) + bf2f(qv.y) + bb.y, 0.f); s += v * ww.y;
        v = fmaxf(bf2f(pv.z) + bf2f(qv.z) + bb.z, 0.f); s += v * ww.z;
        v = fmaxf(bf2f(pv.w) + bf2f(qv.w) + bb.w, 0.f); s += v * ww.w;
      }
#pragma unroll
      for (int off = 32; off > 0; off >>= 1) s += __shfl_down(s, off);
      if (lane == 0) sc[a] = s + b2[0];
    }
  }
  __syncthreads();

  float mx = sc[0];
#pragma unroll
  for (int a = 1; a < 8; ++a) mx = fmaxf(mx, sc[a]);
  float ex[8], den = 0.f;
#pragma unroll
  for (int a = 0; a < 8; ++a) { ex[a] = expf(sc[a] - mx); den += ex[a]; }
  const float inv = 1.0f / den;
  float cf[8];
#pragma unroll
  for (int a = 0; a < 8; ++a) cf[a] = ex[a] * inv * m_s[a];

  if (tid < 384) {
    const int d = tid * 2;
    float a0 = 0.f, a1 = 0.f;
#pragma unroll
    for (int a = 0; a < 8; ++a) {
      const float cfa = cf[a];
      if (cfa != 0.f) {
        const uint32_t w = *(const uint32_t*)(Ebf + (size_t)an_s[a] * HD + d);
        a0 += cfa * bf2f((u16)(w & 0xffffu));
        a1 += cfa * bf2f((u16)(w >> 16));
      }
    }
    const uint32_t packed = (uint32_t)f2bf(a0) | ((uint32_t)f2bf(a1) << 16);
    *(uint32_t*)(dag + (size_t)n * HD + d) = packed;
  }
}

// ---------------- K3: gather dict (bf16) + masked mean pooling ------------
__global__ __launch_bounds__(256) void k_pool(const u16* __restrict__ dag,
                                              const int* __restrict__ ids,
                                              const float* __restrict__ cm,
                                              float* __restrict__ pooled) {
  const int bv = blockIdx.x, tid = threadIdx.x;
  __shared__ int   id_s[48];
  __shared__ float cm_s[48];
  if (tid < 48) { id_s[tid] = ids[bv * 48 + tid]; cm_s[tid] = cm[bv * 48 + tid]; }
  __syncthreads();
  float cnt = 0.f;
  for (int m = 0; m < 48; ++m) cnt += cm_s[m];
  const float scale = 1.0f / fmaxf(cnt, 1.0f);
  if (tid < 192) {
    float4 accv = make_float4(0.f, 0.f, 0.f, 0.f);
    for (int m = 0; m < 48; ++m) {
      const int id = id_s[m];
      const float cv = cm_s[m];
      if (id > 0 && cv != 0.f) {
        ushort4 v = *(const ushort4*)(dag + (size_t)(id - 1) * HD + tid * 4);
        accv.x += cv * bf2f(v.x); accv.y += cv * bf2f(v.y);
        accv.z += cv * bf2f(v.z); accv.w += cv * bf2f(v.w);
      }
    }
    accv.x *= scale; accv.y *= scale; accv.z *= scale; accv.w *= scale;
    *(float4*)(pooled + (size_t)bv * HD + tid * 4) = accv;
  }
}

// ---------------- K4: out = pooled @ wc + bc ------------------------------
__global__ __launch_bounds__(256) void k_out(const float* __restrict__ pooled,
                                             const float* __restrict__ wc,
                                             const float* __restrict__ bc,
                                             float* __restrict__ out) {
  const int b0 = blockIdx.x * TB;
  const int tid = threadIdx.x;
  __shared__ float pl[TB][HD];
  for (int i = tid; i < TB * HD; i += 256) pl[i / HD][i % HD] = pooled[(size_t)b0 * HD + i];
  __syncthreads();
  float a0[TB], a1[TB];
#pragma unroll
  for (int r = 0; r < TB; ++r) { a0[r] = 0.f; a1[r] = 0.f; }
  for (int h = 0; h < HD; ++h) {
    const float w0  = wc[(size_t)h * OUTD + tid];
    const float w1v = wc[(size_t)h * OUTD + tid + 256];
#pragma unroll
    for (int r = 0; r < TB; ++r) { const float p = pl[r][h]; a0[r] += p * w0; a1[r] += p * w1v; }
  }
  const float bc0 = bc[tid], bc1 = bc[tid + 256];
#pragma unroll
  for (int r = 0; r < TB; ++r) {
    out[(size_t)(b0 + r) * OUTD + tid]       = a0[r] + bc0;
    out[(size_t)(b0 + r) * OUTD + tid + 256] = a1[r] + bc1;
  }
}

extern "C" void kernel_launch(void* const* d_in, const int* in_sizes, int n_in,
                              void* d_out, int out_size, void* d_ws, size_t ws_size,
                              hipStream_t stream) {
  const float* E     = (const float*)d_in[0];
  const float* w1    = (const float*)d_in[1];
  const float* b1    = (const float*)d_in[2];
  const float* w2    = (const float*)d_in[3];
  const float* b2    = (const float*)d_in[4];
  const float* wc    = (const float*)d_in[5];
  const float* bc    = (const float*)d_in[6];
  const float* masks = (const float*)d_in[7];
  const float* cm    = (const float*)d_in[8];
  const int*   leaves = (const int*)d_in[9];
  const int*   anc    = (const int*)d_in[10];
  const int*   ids    = (const int*)d_in[11];
  float* out = (float*)d_out;

  if (n_in < 12) return;
  if (in_sizes[0] != NTREE * HD) return;
  if (out_size != NBV * OUTD) return;

  char* ws = (char*)d_ws;
  const size_t szEbf = (size_t)NTREE * HD * 2;
  const size_t szBt  = (size_t)GNN * HD * 2;
  const size_t szPQ  = (size_t)NTREE * GNN * 2;
  const size_t szDag = (size_t)NCODES * HD * 2;
  const size_t szPl  = (size_t)NBV * HD * 4;
  if (ws_size < szEbf + szBt + szPQ + szDag + szPl) return;  // ~196 MB

  u16*   Ebf    = (u16*)ws;            ws += szEbf;
  u16*   Bt     = (u16*)ws;            ws += szBt;
  u16*   PQ     = (u16*)ws;            ws += szPQ;
  u16*   dag    = (u16*)ws;            ws += szDag;
  float* pooled = (float*)ws;          ws += szPl;

  const int nPrep = NBLK_CONV + (GNN * HD + 255) / 256;
  k_prep<<<nPrep, 256, 0, stream>>>(E, Ebf, w1, Bt);
  k_gemm<<<GRID, 512, 0, stream>>>(Ebf, Bt, PQ);
  k_attn<<<NCODES, 512, 0, stream>>>(PQ, Ebf, b1, w2, b2, masks, leaves, anc, dag);
  k_pool<<<NBV, 256, 0, stream>>>(dag, ids, cm, pooled);
  k_out<<<NBV / TB, 256, 0, stream>>>(pooled, wc, bc, out);
}

// Round 9
// 283.436 us; speedup vs baseline: 1.0478x; 1.0478x over previous
//
#include <hip/hip_runtime.h>
#include <stdint.h>

typedef unsigned short u16;
typedef __bf16 bfx8 __attribute__((ext_vector_type(8)));
typedef float f32x4 __attribute__((ext_vector_type(4)));
typedef u16 u16x8 __attribute__((ext_vector_type(8)));

#define HD 768
#define NTREE 40000
#define NCODES 10000
#define GNN 1536
#define OUTD 512
#define NBV 512
#define VNEG (-1e30f)

// GEMM: 128x256 tile, BK=32, 4 waves (2Mx2N, wave=64x128), ring-3 LDS (72KB
// -> 2 blocks/CU), 2 phases/tile, stage t+2, steady-state WAITV(8) only.
#define BM2 128
#define BN2 256
#define BK2 32
#define NKT2 (HD / BK2)                 // 24
#define NMT2 ((NTREE + BM2 - 1) / BM2)  // 313
#define NNT2 (GNN / BN2)                // 6
#define GRID2 (NMT2 * NNT2)             // 1878
#define Q82 (GRID2 / 8)                 // 234
#define R82 (GRID2 % 8)                 // 6

#define WAITV(n) asm volatile("s_waitcnt vmcnt(" #n ")" ::: "memory")

__device__ __forceinline__ float bf2f(u16 u) {
  union { uint32_t i; float f; } v; v.i = ((uint32_t)u) << 16; return v.f;
}
__device__ __forceinline__ u16 f2bf(float f) {
  union { float fl; uint32_t i; } v; v.fl = f;
  uint32_t u = v.i;
  u += 0x7FFFu + ((u >> 16) & 1u);
  return (u16)(u >> 16);
}

// ---------------- K0: fused convE (fp32->bf16) + Bt build -----------------
#define NBLK_CONV 30000  // NTREE*HD/4/256
__global__ void k_prep(const float* __restrict__ E, u16* __restrict__ Ebf,
                       const float* __restrict__ w1, u16* __restrict__ Bt) {
  const int bid = blockIdx.x, tid = threadIdx.x;
  if (bid < NBLK_CONV) {
    const int i = bid * 256 + tid;
    float4 v = ((const float4*)E)[i];
    ushort4 r;
    r.x = f2bf(v.x); r.y = f2bf(v.y); r.z = f2bf(v.z); r.w = f2bf(v.w);
    ((ushort4*)Ebf)[i] = r;
  } else {
    const int idx = (bid - NBLK_CONV) * 256 + tid;
    if (idx < GNN * HD) {
      const int n = idx / HD, k = idx % HD;
      const int srow = k + ((n >= HD) ? HD : 0);
      const int scol = (n >= HD) ? (n - HD) : n;
      Bt[idx] = f2bf(w1[(size_t)srow * HD + scol]);
    }
  }
}

// ---------------- K1: bf16 MFMA GEMM  PQ[40000][1536] = Ebf @ B -----------
// LDS (u16 units): buf b at b*12288; A tile 128x32 at +0 (4096), B tile
// 256x32 at +4096 (8192). Row r at r*32; 16B chunk phys = logical ^ (r&3).
__global__ __launch_bounds__(256, 2) void k_gemm(const u16* __restrict__ A,
                                                 const u16* __restrict__ B,
                                                 u16* __restrict__ C) {
  __shared__ u16 lds[36864];  // 72 KB

  const int tid    = threadIdx.x;
  const int lane   = tid & 63;
  const int wv     = tid >> 6;       // 0..3
  const int wr     = wv >> 1;        // 0..1: M half (64 rows)
  const int wc     = wv & 1;         // 0..1: N half (128 cols)
  const int lane15 = lane & 15;
  const int g      = lane >> 4;      // 0..3: 16B k-chunk within K=32

  // bijective XCD swizzle, nt-minor
  const int orig = blockIdx.x;
  const int xcd = orig & 7, lin = orig >> 3;
  const int wg = (xcd < R82 ? xcd * (Q82 + 1)
                            : R82 * (Q82 + 1) + (xcd - R82) * Q82) + lin;
  const int mt = wg / NNT2, nt = wg % NNT2;
  const int tm = mt * BM2, tn = nt * BN2;

  // staging source offsets (u16 elems; inverse-swizzled global source)
  uint32_t aOff[2], bOff[4];
#pragma unroll
  for (int u = 0; u < 2; ++u) {
    const int idx = u * 256 + tid;           // 16B unit 0..511
    const int r = idx >> 2, ph = idx & 3, c = ph ^ (r & 3);
    int ra = tm + r; if (ra > NTREE - 1) ra = NTREE - 1;
    aOff[u] = (uint32_t)ra * HD + c * 8;
  }
#pragma unroll
  for (int u = 0; u < 4; ++u) {
    const int idx = u * 256 + tid;           // 16B unit 0..1023
    const int r = idx >> 2, ph = idx & 3, c = ph ^ (r & 3);
    bOff[u] = (uint32_t)(tn + r) * HD + c * 8;
  }

#define GLL(SRC, DSTBYTE)                                                      \
  __builtin_amdgcn_global_load_lds(                                            \
      (const __attribute__((address_space(1))) void*)(SRC),                    \
      (__attribute__((address_space(3))) void*)((char*)lds + (DSTBYTE)),       \
      16, 0, 0)

  // per wave: STAGE_A = 2 insts, STAGE_BE = 2, STAGE_BO = 2
#define STAGE_A(TT, BI) do {                                                   \
    _Pragma("unroll") for (int u = 0; u < 2; ++u)                              \
      GLL(A + aOff[u] + (TT) * BK2, (BI) * 24576 + (u * 256 + tid) * 16);      \
  } while (0)
#define STAGE_BE(TT, BI) do {                                                  \
    _Pragma("unroll") for (int u = 0; u < 4; u += 2)                           \
      GLL(B + bOff[u] + (TT) * BK2,                                            \
          (BI) * 24576 + 8192 + (u * 256 + tid) * 16);                         \
  } while (0)
#define STAGE_BO(TT, BI) do {                                                  \
    _Pragma("unroll") for (int u = 1; u < 4; u += 2)                           \
      GLL(B + bOff[u] + (TT) * BK2,                                            \
          (BI) * 24576 + 8192 + (u * 256 + tid) * 16);                         \
  } while (0)

  f32x4 acc[4][8];
#pragma unroll
  for (int i = 0; i < 4; ++i)
#pragma unroll
    for (int j = 0; j < 8; ++j) acc[i][j] = (f32x4){0.f, 0.f, 0.f, 0.f};

  // frag read offsets (u16 elems within a buf)
  int aIdx[4], bIdx[8];
#pragma unroll
  for (int mf = 0; mf < 4; ++mf) {
    const int R = wr * 64 + mf * 16 + lane15;
    aIdx[mf] = R * 32 + ((g ^ (R & 3)) << 3);
  }
#pragma unroll
  for (int nf = 0; nf < 8; ++nf) {
    const int R = wc * 128 + nf * 16 + lane15;
    bIdx[nf] = 4096 + R * 32 + ((g ^ (R & 3)) << 3);
  }

  // prologue: stage tiles 0,1 (12 insts/wave); drain A0,Be0; barrier
  STAGE_A(0, 0); STAGE_BE(0, 0); STAGE_BO(0, 0);
  STAGE_A(1, 1); STAGE_BE(1, 1); STAGE_BO(1, 1);
  WAITV(8);
  __builtin_amdgcn_s_barrier();

  int rb = 0, sb = 2;  // current buf, staged (t+2) buf
  for (int t = 0; t < NKT2; ++t) {
    const int bu = rb * 12288;
    const bool more = (t + 2 < NKT2);
    bfx8 aF[4], bF[4], bG[4];

    // ---- ph0: N-half 0. reads A(4)+B0..3(4). stage A(t+2). ----
#pragma unroll
    for (int mf = 0; mf < 4; ++mf) aF[mf] = *(const bfx8*)&lds[bu + aIdx[mf]];
#pragma unroll
    for (int nf = 0; nf < 4; ++nf) bF[nf] = *(const bfx8*)&lds[bu + bIdx[nf]];
    if (more) STAGE_A(t + 2, sb);
    __builtin_amdgcn_s_setprio(1);
#pragma unroll
    for (int mf = 0; mf < 4; ++mf)
#pragma unroll
      for (int nf = 0; nf < 4; ++nf)
        acc[mf][nf] = __builtin_amdgcn_mfma_f32_16x16x32_bf16(
            aF[mf], bF[nf], acc[mf][nf], 0, 0, 0);
    __builtin_amdgcn_s_setprio(0);
    if (t < NKT2 - 2) { WAITV(8); } else { WAITV(0); }  // drain Bo(t)
    __builtin_amdgcn_s_barrier();

    // ---- ph1: N-half 1. reads B4..7(4), A in regs. stage B(t+2). ----
#pragma unroll
    for (int nf = 0; nf < 4; ++nf) bG[nf] = *(const bfx8*)&lds[bu + bIdx[4 + nf]];
    if (more) { STAGE_BE(t + 2, sb); STAGE_BO(t + 2, sb); }
    __builtin_amdgcn_s_setprio(1);
#pragma unroll
    for (int mf = 0; mf < 4; ++mf)
#pragma unroll
      for (int nf = 0; nf < 4; ++nf)
        acc[mf][4 + nf] = __builtin_amdgcn_mfma_f32_16x16x32_bf16(
            aF[mf], bG[nf], acc[mf][4 + nf], 0, 0, 0);
    __builtin_amdgcn_s_setprio(0);
    if (t < NKT2 - 2) { WAITV(8); }                    // drain A,Be(t+1)
    else if (t == NKT2 - 2) { WAITV(0); }
    __builtin_amdgcn_s_barrier();

    rb = (rb == 2) ? 0 : rb + 1;
    sb = (sb == 2) ? 0 : sb + 1;
  }

  // epilogue: D row = (lane>>4)*4 + rr, col = lane15
  const int r0 = (lane >> 4) * 4;
#pragma unroll
  for (int mf = 0; mf < 4; ++mf) {
#pragma unroll
    for (int nf = 0; nf < 8; ++nf) {
#pragma unroll
      for (int rr = 0; rr < 4; ++rr) {
        const int row = tm + wr * 64 + mf * 16 + r0 + rr;
        if (row < NTREE) {
          const int col = tn + wc * 128 + nf * 16 + lane15;
          C[(size_t)row * GNN + col] = f2bf(acc[mf][nf][rr]);
        }
      }
    }
  }
#undef STAGE_A
#undef STAGE_BE
#undef STAGE_BO
#undef GLL
}

// ---------------- K2: scores + masked softmax + dag_emb (bf16 out) --------
__global__ __launch_bounds__(512) void k_attn(const u16* __restrict__ PQ,
                                              const u16* __restrict__ Ebf,
                                              const float* __restrict__ b1,
                                              const float* __restrict__ w2,
                                              const float* __restrict__ b2,
                                              const float* __restrict__ masks,
                                              const int* __restrict__ leaves,
                                              const int* __restrict__ anc,
                                              u16* __restrict__ dag) {
  const int n = blockIdx.x;
  const int tid = threadIdx.x, lane = tid & 63, wv = tid >> 6;
  __shared__ float sc[8];
  __shared__ float m_s[8];
  __shared__ int   an_s[8];
  __shared__ int   lv_s[8];
  if (tid < 8) {
    an_s[tid] = anc[n * 8 + tid];
    lv_s[tid] = leaves[n * 8 + tid];
    m_s[tid]  = masks[n * 8 + tid];
  }
  __syncthreads();

  {
    const int a = wv;
    const float mm = m_s[a];
    if (mm == 0.f) {
      if (lane == 0) sc[a] = VNEG;
    } else {
      const int l = lv_s[a], an = an_s[a];
      const u16* pr = PQ + (size_t)l * GNN;        // P (cols 0..767)
      const u16* qr = PQ + (size_t)an * GNN + HD;  // Q (cols 768..1535)
      // coalesced: b128 over first 512 cols + b64 over last 256
      u16x8  p1 = *(const u16x8*)(pr + lane * 8);
      u16x8  q1 = *(const u16x8*)(qr + lane * 8);
      ushort4 p2 = *(const ushort4*)(pr + 512 + lane * 4);
      ushort4 q2 = *(const ushort4*)(qr + 512 + lane * 4);
      const float4 bbA = *(const float4*)(b1 + lane * 8);
      const float4 bbB = *(const float4*)(b1 + lane * 8 + 4);
      const float4 bbC = *(const float4*)(b1 + 512 + lane * 4);
      const float4 wwA = *(const float4*)(w2 + lane * 8);
      const float4 wwB = *(const float4*)(w2 + lane * 8 + 4);
      const float4 wwC = *(const float4*)(w2 + 512 + lane * 4);
      float s = 0.f, v;
      v = fmaxf(bf2f(p1[0]) + bf2f(q1[0]) + bbA.x, 0.f); s += v * wwA.x;
      v = fmaxf(bf2f(p1[1]) + bf2f(q1[1]) + bbA.y, 0.f); s += v * wwA.y;
      v = fmaxf(bf2f(p1[2]) + bf2f(q1[2]) + bbA.z, 0.f); s += v * wwA.z;
      v = fmaxf(bf2f(p1[3]) + bf2f(q1[3]) + bbA.w, 0.f); s += v * wwA.w;
      v = fmaxf(bf2f(p1[4]) + bf2f(q1[4]) + bbB.x, 0.f); s += v * wwB.x;
      v = fmaxf(bf2f(p1[5]) + bf2f(q1[5]) + bbB.y, 0.f); s += v * wwB.y;
      v = fmaxf(bf2f(p1[6]) + bf2f(q1[6]) + bbB.z, 0.f); s += v * wwB.z;
      v = fmaxf(bf2f(p1[7]) + bf2f(q1[7]) + bbB.w, 0.f); s += v * wwB.w;
      v = fmaxf(bf2f(p2.x) + bf2f(q2.x) + bbC.x, 0.f);   s += v * wwC.x;
      v = fmaxf(bf2f(p2.y) + bf2f(q2.y) + bbC.y, 0.f);   s += v * wwC.y;
      v = fmaxf(bf2f(p2.z) + bf2f(q2.z) + bbC.z, 0.f);   s += v * wwC.z;
      v = fmaxf(bf2f(p2.w) + bf2f(q2.w) + bbC.w, 0.f);   s += v * wwC.w;
#pragma unroll
      for (int off = 32; off > 0; off >>= 1) s += __shfl_down(s, off);
      if (lane == 0) sc[a] = s + b2[0];
    }
  }
  __syncthreads();

  float mx = sc[0];
#pragma unroll
  for (int a = 1; a < 8; ++a) mx = fmaxf(mx, sc[a]);
  float ex[8], den = 0.f;
#pragma unroll
  for (int a = 0; a < 8; ++a) { ex[a] = expf(sc[a] - mx); den += ex[a]; }
  const float inv = 1.0f / den;
  float cf[8];
#pragma unroll
  for (int a = 0; a < 8; ++a) cf[a] = ex[a] * inv * m_s[a];

  if (tid < 384) {
    const int d = tid * 2;
    float a0 = 0.f, a1 = 0.f;
#pragma unroll
    for (int a = 0; a < 8; ++a) {
      const float cfa = cf[a];
      if (cfa != 0.f) {
        const uint32_t w = *(const uint32_t*)(Ebf + (size_t)an_s[a] * HD + d);
        a0 += cfa * bf2f((u16)(w & 0xffffu));
        a1 += cfa * bf2f((u16)(w >> 16));
      }
    }
    const uint32_t packed = (uint32_t)f2bf(a0) | ((uint32_t)f2bf(a1) << 16);
    *(uint32_t*)(dag + (size_t)n * HD + d) = packed;
  }
}

// ---------------- K3: gather dict (bf16) + masked mean pooling ------------
__global__ __launch_bounds__(256) void k_pool(const u16* __restrict__ dag,
                                              const int* __restrict__ ids,
                                              const float* __restrict__ cm,
                                              float* __restrict__ pooled) {
  const int bv = blockIdx.x, tid = threadIdx.x;
  __shared__ int   id_s[48];
  __shared__ float cm_s[48];
  if (tid < 48) { id_s[tid] = ids[bv * 48 + tid]; cm_s[tid] = cm[bv * 48 + tid]; }
  __syncthreads();
  float cnt = 0.f;
  for (int m = 0; m < 48; ++m) cnt += cm_s[m];
  const float scale = 1.0f / fmaxf(cnt, 1.0f);
  if (tid < 192) {
    float4 accv = make_float4(0.f, 0.f, 0.f, 0.f);
    for (int m = 0; m < 48; ++m) {
      const int id = id_s[m];
      const float cv = cm_s[m];
      if (id > 0 && cv != 0.f) {
        ushort4 v = *(const ushort4*)(dag + (size_t)(id - 1) * HD + tid * 4);
        accv.x += cv * bf2f(v.x); accv.y += cv * bf2f(v.y);
        accv.z += cv * bf2f(v.z); accv.w += cv * bf2f(v.w);
      }
    }
    accv.x *= scale; accv.y *= scale; accv.z *= scale; accv.w *= scale;
    *(float4*)(pooled + (size_t)bv * HD + tid * 4) = accv;
  }
}

// ---------------- K4: out = pooled @ wc + bc (2D LDS mini-GEMM) -----------
// grid 64: (rb 0..7) x (cb 0..7); block = 64x64 out tile, 256 threads (16x16,
// 4x4 outs each), K tiled by 32 with LDS staging of both operands.
__global__ __launch_bounds__(256) void k_out(const float* __restrict__ pooled,
                                             const float* __restrict__ wc,
                                             const float* __restrict__ bc,
                                             float* __restrict__ out) {
  const int rb = blockIdx.x >> 3, cb = blockIdx.x & 7;
  const int tid = threadIdx.x;
  const int ty = tid >> 4, tx = tid & 15;
  __shared__ float pl[64][33];
  __shared__ float wcs[32][64];
  float acc[4][4];
#pragma unroll
  for (int i = 0; i < 4; ++i)
#pragma unroll
    for (int j = 0; j < 4; ++j) acc[i][j] = 0.f;

  for (int kt = 0; kt < HD / 32; ++kt) {
    __syncthreads();
#pragma unroll
    for (int u = 0; u < 2; ++u) {
      const int i = u * 256 + tid;           // 0..511
      const int r = i >> 3, kq = (i & 7) * 4;
      float4 v = *(const float4*)(pooled + (size_t)(rb * 64 + r) * HD + kt * 32 + kq);
      pl[r][kq] = v.x; pl[r][kq + 1] = v.y; pl[r][kq + 2] = v.z; pl[r][kq + 3] = v.w;
    }
#pragma unroll
    for (int u = 0; u < 2; ++u) {
      const int i = u * 256 + tid;
      const int k = i >> 4, cq = (i & 15) * 4;
      *(float4*)&wcs[k][cq] =
          *(const float4*)(wc + (size_t)(kt * 32 + k) * OUTD + cb * 64 + cq);
    }
    __syncthreads();
#pragma unroll 8
    for (int k = 0; k < 32; ++k) {
      const float a0 = pl[ty * 4 + 0][k], a1 = pl[ty * 4 + 1][k];
      const float a2 = pl[ty * 4 + 2][k], a3 = pl[ty * 4 + 3][k];
      const float4 b = *(const float4*)&wcs[k][tx * 4];
      acc[0][0] += a0 * b.x; acc[0][1] += a0 * b.y; acc[0][2] += a0 * b.z; acc[0][3] += a0 * b.w;
      acc[1][0] += a1 * b.x; acc[1][1] += a1 * b.y; acc[1][2] += a1 * b.z; acc[1][3] += a1 * b.w;
      acc[2][0] += a2 * b.x; acc[2][1] += a2 * b.y; acc[2][2] += a2 * b.z; acc[2][3] += a2 * b.w;
      acc[3][0] += a3 * b.x; acc[3][1] += a3 * b.y; acc[3][2] += a3 * b.z; acc[3][3] += a3 * b.w;
    }
  }
#pragma unroll
  for (int i = 0; i < 4; ++i) {
#pragma unroll
    for (int j = 0; j < 4; ++j) {
      const int row = rb * 64 + ty * 4 + i;
      const int col = cb * 64 + tx * 4 + j;
      out[(size_t)row * OUTD + col] = acc[i][j] + bc[col];
    }
  }
}

extern "C" void kernel_launch(void* const* d_in, const int* in_sizes, int n_in,
                              void* d_out, int out_size, void* d_ws, size_t ws_size,
                              hipStream_t stream) {
  const float* E     = (const float*)d_in[0];
  const float* w1    = (const float*)d_in[1];
  const float* b1    = (const float*)d_in[2];
  const float* w2    = (const float*)d_in[3];
  const float* b2    = (const float*)d_in[4];
  const float* wc    = (const float*)d_in[5];
  const float* bc    = (const float*)d_in[6];
  const float* masks = (const float*)d_in[7];
  const float* cm    = (const float*)d_in[8];
  const int*   leaves = (const int*)d_in[9];
  const int*   anc    = (const int*)d_in[10];
  const int*   ids    = (const int*)d_in[11];
  float* out = (float*)d_out;

  if (n_in < 12) return;
  if (in_sizes[0] != NTREE * HD) return;
  if (out_size != NBV * OUTD) return;

  char* ws = (char*)d_ws;
  const size_t szEbf = (size_t)NTREE * HD * 2;
  const size_t szBt  = (size_t)GNN * HD * 2;
  const size_t szPQ  = (size_t)NTREE * GNN * 2;
  const size_t szDag = (size_t)NCODES * HD * 2;
  const size_t szPl  = (size_t)NBV * HD * 4;
  if (ws_size < szEbf + szBt + szPQ + szDag + szPl) return;  // ~196 MB

  u16*   Ebf    = (u16*)ws;            ws += szEbf;
  u16*   Bt     = (u16*)ws;            ws += szBt;
  u16*   PQ     = (u16*)ws;            ws += szPQ;
  u16*   dag    = (u16*)ws;            ws += szDag;
  float* pooled = (float*)ws;          ws += szPl;

  const int nPrep = NBLK_CONV + (GNN * HD + 255) / 256;
  k_prep<<<nPrep, 256, 0, stream>>>(E, Ebf, w1, Bt);
  k_gemm<<<GRID2, 256, 0, stream>>>(Ebf, Bt, PQ);
  k_attn<<<NCODES, 512, 0, stream>>>(PQ, Ebf, b1, w2, b2, masks, leaves, anc, dag);
  k_pool<<<NBV, 256, 0, stream>>>(dag, ids, cm, pooled);
  k_out<<<64, 256, 0, stream>>>(pooled, wc, bc, out);
}

// Round 10
// 282.489 us; speedup vs baseline: 1.0513x; 1.0034x over previous
//
#include <hip/hip_runtime.h>
#include <stdint.h>

typedef unsigned short u16;
typedef __bf16 bfx8 __attribute__((ext_vector_type(8)));
typedef float f32x4 __attribute__((ext_vector_type(4)));
typedef u16 u16x8 __attribute__((ext_vector_type(8)));

#define HD 768
#define NTREE 40000
#define NCODES 10000
#define GNN 1536
#define OUTD 512
#define NBV 512
#define VNEG (-1e30f)

// GEMM: 128x256 tile, BK=32, 4 waves (2Mx2N, wave=64x128), ring-3 LDS (72KB
// -> 2 blocks/CU), 2 phases/tile, stage t+2, steady-state WAITV(8) only.
// Superrow swizzle (R6): superrow s=row>>1 (128B); slot p = ((row&1)<<2|g) ^ (s&7).
#define BM2 128
#define BN2 256
#define BK2 32
#define NKT2 (HD / BK2)                 // 24
#define NMT2 ((NTREE + BM2 - 1) / BM2)  // 313
#define NNT2 (GNN / BN2)                // 6
#define GRID2 (NMT2 * NNT2)             // 1878
#define Q82 (GRID2 / 8)                 // 234
#define R82 (GRID2 % 8)                 // 6

#define WAITV(n) asm volatile("s_waitcnt vmcnt(" #n ")" ::: "memory")

__device__ __forceinline__ float bf2f(u16 u) {
  union { uint32_t i; float f; } v; v.i = ((uint32_t)u) << 16; return v.f;
}
__device__ __forceinline__ u16 f2bf(float f) {
  union { float fl; uint32_t i; } v; v.fl = f;
  uint32_t u = v.i;
  u += 0x7FFFu + ((u >> 16) & 1u);
  return (u16)(u >> 16);
}

// ---------------- K0: fused convE (fp32->bf16) + Bt build -----------------
#define NBLK_CONV 30000  // NTREE*HD/4/256
__global__ void k_prep(const float* __restrict__ E, u16* __restrict__ Ebf,
                       const float* __restrict__ w1, u16* __restrict__ Bt) {
  const int bid = blockIdx.x, tid = threadIdx.x;
  if (bid < NBLK_CONV) {
    const int i = bid * 256 + tid;
    float4 v = ((const float4*)E)[i];
    ushort4 r;
    r.x = f2bf(v.x); r.y = f2bf(v.y); r.z = f2bf(v.z); r.w = f2bf(v.w);
    ((ushort4*)Ebf)[i] = r;
  } else {
    const int idx = (bid - NBLK_CONV) * 256 + tid;
    if (idx < GNN * HD) {
      const int n = idx / HD, k = idx % HD;
      const int srow = k + ((n >= HD) ? HD : 0);
      const int scol = (n >= HD) ? (n - HD) : n;
      Bt[idx] = f2bf(w1[(size_t)srow * HD + scol]);
    }
  }
}

// ---------------- K1: bf16 MFMA GEMM  PQ[40000][1536] = Ebf @ B -----------
// LDS (u16 units): buf b at b*12288; A tile 128x32 at +0 (4096 u16), B tile
// 256x32 at +4096 (8192 u16). Superrow s at s*64 u16; 16B slot p at p*8.
__global__ __launch_bounds__(256, 2) void k_gemm(const u16* __restrict__ A,
                                                 const u16* __restrict__ B,
                                                 u16* __restrict__ C) {
  __shared__ u16 lds[36864];  // 72 KB

  const int tid    = threadIdx.x;
  const int lane   = tid & 63;
  const int wv     = tid >> 6;       // 0..3
  const int wr     = wv >> 1;        // 0..1: M half (64 rows)
  const int wc     = wv & 1;         // 0..1: N half (128 cols)
  const int lane15 = lane & 15;
  const int g      = lane >> 4;      // 0..3: 16B k-chunk within K=32

  // bijective XCD swizzle, nt-minor
  const int orig = blockIdx.x;
  const int xcd = orig & 7, lin = orig >> 3;
  const int wg = (xcd < R82 ? xcd * (Q82 + 1)
                            : R82 * (Q82 + 1) + (xcd - R82) * Q82) + lin;
  const int mt = wg / NNT2, nt = wg % NNT2;
  const int tm = mt * BM2, tn = nt * BN2;

  // staging source offsets (u16 elems; inverse superrow-swizzled source)
  uint32_t aOff[2], bOff[4];
#pragma unroll
  for (int u = 0; u < 2; ++u) {
    const int idx  = u * 256 + tid;          // 16B unit 0..511
    const int s    = idx >> 3;               // superrow 0..63
    const int phys = idx & 7;
    const int slot = phys ^ (s & 7);
    const int row  = 2 * s + (slot >> 2);
    const int c    = slot & 3;
    int ra = tm + row; if (ra > NTREE - 1) ra = NTREE - 1;
    aOff[u] = (uint32_t)ra * HD + c * 8;
  }
#pragma unroll
  for (int u = 0; u < 4; ++u) {
    const int idx  = u * 256 + tid;          // 16B unit 0..1023
    const int s    = idx >> 3;               // superrow 0..127
    const int phys = idx & 7;
    const int slot = phys ^ (s & 7);
    const int row  = 2 * s + (slot >> 2);
    const int c    = slot & 3;
    bOff[u] = (uint32_t)(tn + row) * HD + c * 8;
  }

#define GLL(SRC, DSTBYTE)                                                      \
  __builtin_amdgcn_global_load_lds(                                            \
      (const __attribute__((address_space(1))) void*)(SRC),                    \
      (__attribute__((address_space(3))) void*)((char*)lds + (DSTBYTE)),       \
      16, 0, 0)

#define STAGE_A(TT, BI) do {                                                   \
    _Pragma("unroll") for (int u = 0; u < 2; ++u)                              \
      GLL(A + aOff[u] + (TT) * BK2, (BI) * 24576 + (u * 256 + tid) * 16);      \
  } while (0)
#define STAGE_BE(TT, BI) do {                                                  \
    _Pragma("unroll") for (int u = 0; u < 4; u += 2)                           \
      GLL(B + bOff[u] + (TT) * BK2,                                            \
          (BI) * 24576 + 8192 + (u * 256 + tid) * 16);                         \
  } while (0)
#define STAGE_BO(TT, BI) do {                                                  \
    _Pragma("unroll") for (int u = 1; u < 4; u += 2)                           \
      GLL(B + bOff[u] + (TT) * BK2,                                            \
          (BI) * 24576 + 8192 + (u * 256 + tid) * 16);                         \
  } while (0)

  f32x4 acc[4][8];
#pragma unroll
  for (int i = 0; i < 4; ++i)
#pragma unroll
    for (int j = 0; j < 8; ++j) acc[i][j] = (f32x4){0.f, 0.f, 0.f, 0.f};

  // frag read offsets (u16 units within a buf): row R, chunk g ->
  // s=R>>1, slot=((R&1)<<2)|g, phys=slot^(s&7), off = s*64 + phys*8
  int aIdx[4], bIdx[8];
#pragma unroll
  for (int mf = 0; mf < 4; ++mf) {
    const int R = wr * 64 + mf * 16 + lane15;
    const int s = R >> 1, slot = ((R & 1) << 2) | g, phys = slot ^ (s & 7);
    aIdx[mf] = s * 64 + phys * 8;
  }
#pragma unroll
  for (int nf = 0; nf < 8; ++nf) {
    const int R = wc * 128 + nf * 16 + lane15;
    const int s = R >> 1, slot = ((R & 1) << 2) | g, phys = slot ^ (s & 7);
    bIdx[nf] = 4096 + s * 64 + phys * 8;
  }

  // prologue: stage tiles 0,1 (12 insts/wave); drain tile0; barrier
  STAGE_A(0, 0); STAGE_BE(0, 0); STAGE_BO(0, 0);
  STAGE_A(1, 1); STAGE_BE(1, 1); STAGE_BO(1, 1);
  WAITV(8);
  __builtin_amdgcn_s_barrier();

  int rb = 0, sb = 2;  // current buf, staged (t+2) buf
  for (int t = 0; t < NKT2; ++t) {
    const int bu = rb * 12288;
    const bool more = (t + 2 < NKT2);
    bfx8 aF[4], bF[4], bG[4];

    // ---- ph0: N-half 0. reads A(4)+B0..3(4). stage A(t+2). ----
#pragma unroll
    for (int mf = 0; mf < 4; ++mf) aF[mf] = *(const bfx8*)&lds[bu + aIdx[mf]];
#pragma unroll
    for (int nf = 0; nf < 4; ++nf) bF[nf] = *(const bfx8*)&lds[bu + bIdx[nf]];
    if (more) STAGE_A(t + 2, sb);
    __builtin_amdgcn_s_setprio(1);
#pragma unroll
    for (int mf = 0; mf < 4; ++mf)
#pragma unroll
      for (int nf = 0; nf < 4; ++nf)
        acc[mf][nf] = __builtin_amdgcn_mfma_f32_16x16x32_bf16(
            aF[mf], bF[nf], acc[mf][nf], 0, 0, 0);
    __builtin_amdgcn_s_setprio(0);
    if (t < NKT2 - 2) { WAITV(8); } else { WAITV(0); }  // drain Bo(t)
    __builtin_amdgcn_s_barrier();

    // ---- ph1: N-half 1. reads B4..7(4), A in regs. stage B(t+2). ----
#pragma unroll
    for (int nf = 0; nf < 4; ++nf) bG[nf] = *(const bfx8*)&lds[bu + bIdx[4 + nf]];
    if (more) { STAGE_BE(t + 2, sb); STAGE_BO(t + 2, sb); }
    __builtin_amdgcn_s_setprio(1);
#pragma unroll
    for (int mf = 0; mf < 4; ++mf)
#pragma unroll
      for (int nf = 0; nf < 4; ++nf)
        acc[mf][4 + nf] = __builtin_amdgcn_mfma_f32_16x16x32_bf16(
            aF[mf], bG[nf], acc[mf][4 + nf], 0, 0, 0);
    __builtin_amdgcn_s_setprio(0);
    if (t < NKT2 - 2) { WAITV(8); }                    // drain A,Be(t+1)
    else if (t == NKT2 - 2) { WAITV(0); }
    __builtin_amdgcn_s_barrier();

    rb = (rb == 2) ? 0 : rb + 1;
    sb = (sb == 2) ? 0 : sb + 1;
  }

  // epilogue: D row = (lane>>4)*4 + rr, col = lane15
  const int r0 = (lane >> 4) * 4;
#pragma unroll
  for (int mf = 0; mf < 4; ++mf) {
#pragma unroll
    for (int nf = 0; nf < 8; ++nf) {
#pragma unroll
      for (int rr = 0; rr < 4; ++rr) {
        const int row = tm + wr * 64 + mf * 16 + r0 + rr;
        if (row < NTREE) {
          const int col = tn + wc * 128 + nf * 16 + lane15;
          C[(size_t)row * GNN + col] = f2bf(acc[mf][nf][rr]);
        }
      }
    }
  }
#undef STAGE_A
#undef STAGE_BE
#undef STAGE_BO
#undef GLL
}

// ---------------- K2: scores + masked softmax + dag_emb (bf16 out) --------
__global__ __launch_bounds__(512) void k_attn(const u16* __restrict__ PQ,
                                              const u16* __restrict__ Ebf,
                                              const float* __restrict__ b1,
                                              const float* __restrict__ w2,
                                              const float* __restrict__ b2,
                                              const float* __restrict__ masks,
                                              const int* __restrict__ leaves,
                                              const int* __restrict__ anc,
                                              u16* __restrict__ dag) {
  const int n = blockIdx.x;
  const int tid = threadIdx.x, lane = tid & 63, wv = tid >> 6;
  __shared__ float sc[8];
  __shared__ float m_s[8];
  __shared__ int   an_s[8];
  __shared__ int   lv_s[8];
  if (tid < 8) {
    an_s[tid] = anc[n * 8 + tid];
    lv_s[tid] = leaves[n * 8 + tid];
    m_s[tid]  = masks[n * 8 + tid];
  }
  __syncthreads();

  {
    const int a = wv;
    const float mm = m_s[a];
    if (mm == 0.f) {
      if (lane == 0) sc[a] = VNEG;
    } else {
      const int l = lv_s[a], an = an_s[a];
      const u16* pr = PQ + (size_t)l * GNN;        // P (cols 0..767)
      const u16* qr = PQ + (size_t)an * GNN + HD;  // Q (cols 768..1535)
      u16x8  p1 = *(const u16x8*)(pr + lane * 8);
      u16x8  q1 = *(const u16x8*)(qr + lane * 8);
      ushort4 p2 = *(const ushort4*)(pr + 512 + lane * 4);
      ushort4 q2 = *(const ushort4*)(qr + 512 + lane * 4);
      const float4 bbA = *(const float4*)(b1 + lane * 8);
      const float4 bbB = *(const float4*)(b1 + lane * 8 + 4);
      const float4 bbC = *(const float4*)(b1 + 512 + lane * 4);
      const float4 wwA = *(const float4*)(w2 + lane * 8);
      const float4 wwB = *(const float4*)(w2 + lane * 8 + 4);
      const float4 wwC = *(const float4*)(w2 + 512 + lane * 4);
      float s = 0.f, v;
      v = fmaxf(bf2f(p1[0]) + bf2f(q1[0]) + bbA.x, 0.f); s += v * wwA.x;
      v = fmaxf(bf2f(p1[1]) + bf2f(q1[1]) + bbA.y, 0.f); s += v * wwA.y;
      v = fmaxf(bf2f(p1[2]) + bf2f(q1[2]) + bbA.z, 0.f); s += v * wwA.z;
      v = fmaxf(bf2f(p1[3]) + bf2f(q1[3]) + bbA.w, 0.f); s += v * wwA.w;
      v = fmaxf(bf2f(p1[4]) + bf2f(q1[4]) + bbB.x, 0.f); s += v * wwB.x;
      v = fmaxf(bf2f(p1[5]) + bf2f(q1[5]) + bbB.y, 0.f); s += v * wwB.y;
      v = fmaxf(bf2f(p1[6]) + bf2f(q1[6]) + bbB.z, 0.f); s += v * wwB.z;
      v = fmaxf(bf2f(p1[7]) + bf2f(q1[7]) + bbB.w, 0.f); s += v * wwB.w;
      v = fmaxf(bf2f(p2.x) + bf2f(q2.x) + bbC.x, 0.f);   s += v * wwC.x;
      v = fmaxf(bf2f(p2.y) + bf2f(q2.y) + bbC.y, 0.f);   s += v * wwC.y;
      v = fmaxf(bf2f(p2.z) + bf2f(q2.z) + bbC.z, 0.f);   s += v * wwC.z;
      v = fmaxf(bf2f(p2.w) + bf2f(q2.w) + bbC.w, 0.f);   s += v * wwC.w;
#pragma unroll
      for (int off = 32; off > 0; off >>= 1) s += __shfl_down(s, off);
      if (lane == 0) sc[a] = s + b2[0];
    }
  }
  __syncthreads();

  float mx = sc[0];
#pragma unroll
  for (int a = 1; a < 8; ++a) mx = fmaxf(mx, sc[a]);
  float ex[8], den = 0.f;
#pragma unroll
  for (int a = 0; a < 8; ++a) { ex[a] = expf(sc[a] - mx); den += ex[a]; }
  const float inv = 1.0f / den;
  float cf[8];
#pragma unroll
  for (int a = 0; a < 8; ++a) cf[a] = ex[a] * inv * m_s[a];

  if (tid < 384) {
    const int d = tid * 2;
    float a0 = 0.f, a1 = 0.f;
#pragma unroll
    for (int a = 0; a < 8; ++a) {
      const float cfa = cf[a];
      if (cfa != 0.f) {
        const uint32_t w = *(const uint32_t*)(Ebf + (size_t)an_s[a] * HD + d);
        a0 += cfa * bf2f((u16)(w & 0xffffu));
        a1 += cfa * bf2f((u16)(w >> 16));
      }
    }
    const uint32_t packed = (uint32_t)f2bf(a0) | ((uint32_t)f2bf(a1) << 16);
    *(uint32_t*)(dag + (size_t)n * HD + d) = packed;
  }
}

// ---------------- K3: gather dict (bf16) + masked mean pooling ------------
__global__ __launch_bounds__(256) void k_pool(const u16* __restrict__ dag,
                                              const int* __restrict__ ids,
                                              const float* __restrict__ cm,
                                              float* __restrict__ pooled) {
  const int bv = blockIdx.x, tid = threadIdx.x;
  __shared__ int   id_s[48];
  __shared__ float cm_s[48];
  if (tid < 48) { id_s[tid] = ids[bv * 48 + tid]; cm_s[tid] = cm[bv * 48 + tid]; }
  __syncthreads();
  float cnt = 0.f;
  for (int m = 0; m < 48; ++m) cnt += cm_s[m];
  const float scale = 1.0f / fmaxf(cnt, 1.0f);
  if (tid < 192) {
    float4 accv = make_float4(0.f, 0.f, 0.f, 0.f);
    for (int m = 0; m < 48; ++m) {
      const int id = id_s[m];
      const float cv = cm_s[m];
      if (id > 0 && cv != 0.f) {
        ushort4 v = *(const ushort4*)(dag + (size_t)(id - 1) * HD + tid * 4);
        accv.x += cv * bf2f(v.x); accv.y += cv * bf2f(v.y);
        accv.z += cv * bf2f(v.z); accv.w += cv * bf2f(v.w);
      }
    }
    accv.x *= scale; accv.y *= scale; accv.z *= scale; accv.w *= scale;
    *(float4*)(pooled + (size_t)bv * HD + tid * 4) = accv;
  }
}

// ---------------- K4: out = pooled @ wc + bc (2D LDS mini-GEMM) -----------
__global__ __launch_bounds__(256) void k_out(const float* __restrict__ pooled,
                                             const float* __restrict__ wc,
                                             const float* __restrict__ bc,
                                             float* __restrict__ out) {
  const int rb = blockIdx.x >> 3, cb = blockIdx.x & 7;
  const int tid = threadIdx.x;
  const int ty = tid >> 4, tx = tid & 15;
  __shared__ float pl[64][33];
  __shared__ float wcs[32][64];
  float acc[4][4];
#pragma unroll
  for (int i = 0; i < 4; ++i)
#pragma unroll
    for (int j = 0; j < 4; ++j) acc[i][j] = 0.f;

  for (int kt = 0; kt < HD / 32; ++kt) {
    __syncthreads();
#pragma unroll
    for (int u = 0; u < 2; ++u) {
      const int i = u * 256 + tid;           // 0..511
      const int r = i >> 3, kq = (i & 7) * 4;
      float4 v = *(const float4*)(pooled + (size_t)(rb * 64 + r) * HD + kt * 32 + kq);
      pl[r][kq] = v.x; pl[r][kq + 1] = v.y; pl[r][kq + 2] = v.z; pl[r][kq + 3] = v.w;
    }
#pragma unroll
    for (int u = 0; u < 2; ++u) {
      const int i = u * 256 + tid;
      const int k = i >> 4, cq = (i & 15) * 4;
      *(float4*)&wcs[k][cq] =
          *(const float4*)(wc + (size_t)(kt * 32 + k) * OUTD + cb * 64 + cq);
    }
    __syncthreads();
#pragma unroll 8
    for (int k = 0; k < 32; ++k) {
      const float a0 = pl[ty * 4 + 0][k], a1 = pl[ty * 4 + 1][k];
      const float a2 = pl[ty * 4 + 2][k], a3 = pl[ty * 4 + 3][k];
      const float4 b = *(const float4*)&wcs[k][tx * 4];
      acc[0][0] += a0 * b.x; acc[0][1] += a0 * b.y; acc[0][2] += a0 * b.z; acc[0][3] += a0 * b.w;
      acc[1][0] += a1 * b.x; acc[1][1] += a1 * b.y; acc[1][2] += a1 * b.z; acc[1][3] += a1 * b.w;
      acc[2][0] += a2 * b.x; acc[2][1] += a2 * b.y; acc[2][2] += a2 * b.z; acc[2][3] += a2 * b.w;
      acc[3][0] += a3 * b.x; acc[3][1] += a3 * b.y; acc[3][2] += a3 * b.z; acc[3][3] += a3 * b.w;
    }
  }
#pragma unroll
  for (int i = 0; i < 4; ++i) {
#pragma unroll
    for (int j = 0; j < 4; ++j) {
      const int row = rb * 64 + ty * 4 + i;
      const int col = cb * 64 + tx * 4 + j;
      out[(size_t)row * OUTD + col] = acc[i][j] + bc[col];
    }
  }
}

extern "C" void kernel_launch(void* const* d_in, const int* in_sizes, int n_in,
                              void* d_out, int out_size, void* d_ws, size_t ws_size,
                              hipStream_t stream) {
  const float* E     = (const float*)d_in[0];
  const float* w1    = (const float*)d_in[1];
  const float* b1    = (const float*)d_in[2];
  const float* w2    = (const float*)d_in[3];
  const float* b2    = (const float*)d_in[4];
  const float* wc    = (const float*)d_in[5];
  const float* bc    = (const float*)d_in[6];
  const float* masks = (const float*)d_in[7];
  const float* cm    = (const float*)d_in[8];
  const int*   leaves = (const int*)d_in[9];
  const int*   anc    = (const int*)d_in[10];
  const int*   ids    = (const int*)d_in[11];
  float* out = (float*)d_out;

  if (n_in < 12) return;
  if (in_sizes[0] != NTREE * HD) return;
  if (out_size != NBV * OUTD) return;

  char* ws = (char*)d_ws;
  const size_t szEbf = (size_t)NTREE * HD * 2;
  const size_t szBt  = (size_t)GNN * HD * 2;
  const size_t szPQ  = (size_t)NTREE * GNN * 2;
  const size_t szDag = (size_t)NCODES * HD * 2;
  const size_t szPl  = (size_t)NBV * HD * 4;
  if (ws_size < szEbf + szBt + szPQ + szDag + szPl) return;  // ~196 MB

  u16*   Ebf    = (u16*)ws;            ws += szEbf;
  u16*   Bt     = (u16*)ws;            ws += szBt;
  u16*   PQ     = (u16*)ws;            ws += szPQ;
  u16*   dag    = (u16*)ws;            ws += szDag;
  float* pooled = (float*)ws;          ws += szPl;

  const int nPrep = NBLK_CONV + (GNN * HD + 255) / 256;
  k_prep<<<nPrep, 256, 0, stream>>>(E, Ebf, w1, Bt);
  k_gemm<<<GRID2, 256, 0, stream>>>(Ebf, Bt, PQ);
  k_attn<<<NCODES, 512, 0, stream>>>(PQ, Ebf, b1, w2, b2, masks, leaves, anc, dag);
  k_pool<<<NBV, 256, 0, stream>>>(dag, ids, cm, pooled);
  k_out<<<64, 256, 0, stream>>>(pooled, wc, bc, out);
}

// Round 11
// 269.021 us; speedup vs baseline: 1.1039x; 1.0501x over previous
//
#include <hip/hip_runtime.h>
#include <stdint.h>

typedef unsigned short u16;
typedef __bf16 bfx8 __attribute__((ext_vector_type(8)));
typedef float f32x4 __attribute__((ext_vector_type(4)));
typedef u16 u16x8 __attribute__((ext_vector_type(8)));

#define HD 768
#define NTREE 40000
#define NCODES 10000
#define GNN 1536
#define OUTD 512
#define NBV 512
#define VNEG (-1e30f)

// GEMM (R5 best-measured): 256x256 tile, BK=64, 8 waves 2Mx4N (128x64/wave),
// 4 phases/K-tile, frag reads one phase ahead (counted lgkmcnt), 2-deep dbuf.
#define BM 256
#define BN 256
#define BK 64
#define NKT (HD / BK)                // 12
#define NMT ((NTREE + BM - 1) / BM)  // 157
#define NNT (GNN / BN)               // 6
#define GRID (NMT * NNT)             // 942
#define Q8 (GRID / 8)                // 117
#define R8 (GRID % 8)                // 6

#define WAITV(n) asm volatile("s_waitcnt vmcnt(" #n ")" ::: "memory")
#define LGKM(n)  asm volatile("s_waitcnt lgkmcnt(" #n ")" ::: "memory")

__device__ __forceinline__ float bf2f(u16 u) {
  union { uint32_t i; float f; } v; v.i = ((uint32_t)u) << 16; return v.f;
}
__device__ __forceinline__ u16 f2bf(float f) {
  union { float fl; uint32_t i; } v; v.fl = f;
  uint32_t u = v.i;
  u += 0x7FFFu + ((u >> 16) & 1u);
  return (u16)(u >> 16);
}

// ---------------- K0: fused convE (fp32->bf16) + Bt build -----------------
#define NBLK_CONV 30000  // NTREE*HD/4/256
__global__ void k_prep(const float* __restrict__ E, u16* __restrict__ Ebf,
                       const float* __restrict__ w1, u16* __restrict__ Bt) {
  const int bid = blockIdx.x, tid = threadIdx.x;
  if (bid < NBLK_CONV) {
    const int i = bid * 256 + tid;
    float4 v = ((const float4*)E)[i];
    ushort4 r;
    r.x = f2bf(v.x); r.y = f2bf(v.y); r.z = f2bf(v.z); r.w = f2bf(v.w);
    ((ushort4*)Ebf)[i] = r;
  } else {
    const int idx = (bid - NBLK_CONV) * 256 + tid;
    if (idx < GNN * HD) {
      const int n = idx / HD, k = idx % HD;
      const int srow = k + ((n >= HD) ? HD : 0);
      const int scol = (n >= HD) ? (n - HD) : n;
      Bt[idx] = f2bf(w1[(size_t)srow * HD + scol]);
    }
  }
}

// ---------------- K1: bf16 MFMA GEMM  PQ[40000][1536] = Ebf @ B -----------
// LDS byte map: A buf b at b*32768; B buf b at 65536 + b*32768.
// Row r at r*128 bytes; 16B chunk phys = logical ^ (r&7) (both-sides swizzle).
__global__ __launch_bounds__(512, 2) void k_gemm(const u16* __restrict__ A,
                                                 const u16* __restrict__ B,
                                                 u16* __restrict__ C) {
  __shared__ u16 lds[65536];  // 128 KB

  const int tid    = threadIdx.x;
  const int lane   = tid & 63;
  const int wv     = tid >> 6;       // 0..7
  const int wm     = wv >> 2;        // 0..1: wave's M half (rows wm*128..+127)
  const int wn2    = wv & 3;         // 0..3: wave's N strip (cols wn2*64..+63)
  const int lane15 = lane & 15;
  const int g      = lane >> 4;      // 0..3: 16B chunk within K=32 step

  // bijective XCD swizzle, nt-minor (blocks on one XCD share the A panel)
  const int orig = blockIdx.x;
  const int xcd = orig & 7, lin = orig >> 3;
  const int wg = (xcd < R8 ? xcd * (Q8 + 1) : R8 * (Q8 + 1) + (xcd - R8) * Q8) + lin;
  const int mt = wg / NNT, nt = wg % NNT;
  const int tm = mt * BM, tn = nt * BN;

  // staging source offsets (u16 elements; pre-swizzled global source)
  uint32_t aOff[2][2], bOff[2][2];  // [u][half]
#pragma unroll
  for (int u = 0; u < 2; ++u) {
    const int o    = u * 8192 + tid * 16;          // byte in 16KB half
    const int rloc = o >> 7;                        // local row 0..127
    const int c    = ((o >> 4) & 7) ^ (rloc & 7);   // logical 16B chunk
#pragma unroll
    for (int h = 0; h < 2; ++h) {
      int ra = tm + h * 128 + rloc; if (ra > NTREE - 1) ra = NTREE - 1;
      aOff[u][h] = (uint32_t)ra * HD + c * 8;
      bOff[u][h] = (uint32_t)(tn + h * 128 + rloc) * HD + c * 8;
    }
  }

#define STAGE_A(MH, NB, TT) do {                                               \
    _Pragma("unroll") for (int u = 0; u < 2; ++u)                              \
      __builtin_amdgcn_global_load_lds(                                        \
        (const __attribute__((address_space(1))) void*)(A + aOff[u][MH] + (TT) * BK), \
        (__attribute__((address_space(3))) void*)((char*)lds + (NB) * 32768 +  \
            (MH) * 16384 + u * 8192 + tid * 16),                               \
        16, 0, 0);                                                             \
  } while (0)

#define STAGE_B(NH, NB, TT) do {                                               \
    _Pragma("unroll") for (int u = 0; u < 2; ++u)                              \
      __builtin_amdgcn_global_load_lds(                                        \
        (const __attribute__((address_space(1))) void*)(B + bOff[u][NH] + (TT) * BK), \
        (__attribute__((address_space(3))) void*)((char*)lds + 65536 +         \
            (NB) * 32768 + (NH) * 16384 + u * 8192 + tid * 16),                \
        16, 0, 0);                                                             \
  } while (0)

  f32x4 acc[8][4];
#pragma unroll
  for (int i = 0; i < 8; ++i)
#pragma unroll
    for (int j = 0; j < 4; ++j) acc[i][j] = (f32x4){0.f, 0.f, 0.f, 0.f};

  // swizzled read column offset (u16 elems) per k-step; row&7 == lane15&7
  int colz[2];
  colz[0] = ((0 * 4 + g) ^ (lane15 & 7)) * 8;
  colz[1] = ((1 * 4 + g) ^ (lane15 & 7)) * 8;
  const int aBase = (wm * 128 + lane15) * 64;  // u16 elems, row stride 64
  const int bBase = (wn2 * 64 + lane15) * 64;

  bfx8 aF0[4], aF1[4], bF0[4], bF1[4];  // named ping-pong frag buffers

#define READ_A(DST, MH, KS, BA) do {                                           \
    const int _a = (BA) + aBase + (MH) * 4096 + colz[KS];                      \
    _Pragma("unroll") for (int i = 0; i < 4; ++i)                              \
      DST[i] = *(const bfx8*)&lds[_a + i * 1024];                              \
  } while (0)

#define READ_B(DST, KS, BB) do {                                               \
    const int _b = (BB) + bBase + colz[KS];                                    \
    _Pragma("unroll") for (int j = 0; j < 4; ++j)                              \
      DST[j] = *(const bfx8*)&lds[_b + j * 1024];                              \
  } while (0)

#define MFMA16(MH, AFR, BFR) do {                                              \
    __builtin_amdgcn_s_setprio(1);                                             \
    _Pragma("unroll") for (int i = 0; i < 4; ++i)                              \
      _Pragma("unroll") for (int j = 0; j < 4; ++j)                            \
        acc[(MH) * 4 + i][j] = __builtin_amdgcn_mfma_f32_16x16x32_bf16(        \
            AFR[i], BFR[j], acc[(MH) * 4 + i][j], 0, 0, 0);                    \
    __builtin_amdgcn_s_setprio(0);                                             \
  } while (0)

  // prologue: stage tile 0 into buf 0, drain, barrier, prefetch p0 frags
  STAGE_A(0, 0, 0);
  STAGE_A(1, 0, 0);
  STAGE_B(0, 0, 0);
  STAGE_B(1, 0, 0);
  WAITV(0);
  __builtin_amdgcn_s_barrier();
  READ_A(aF0, 0, 0, 0);        // tile0 A-lo ks0 (4 reads, left in flight)
  READ_B(bF0, 0, 32768);       // tile0 B ks0   (4 reads, left in flight)

  for (int t = 0; t < NKT; ++t) {
    const int bA  = (t & 1) * 16384;          // u16 index of A buf (tile t)
    const int bB  = 32768 + (t & 1) * 16384;  // u16 index of B buf (tile t)
    const int nb  = (t + 1) & 1;
    const int nbA = nb * 16384;
    const int nbB = 32768 + nb * 16384;
    const bool more = (t + 1 < NKT);

    // ---- p0: MFMA (A-lo, ks0); prefetch A-hi ks0; stage A(t+1) ----
    READ_A(aF1, 1, 0, bA);
    if (more) { STAGE_A(0, nb, t + 1); STAGE_A(1, nb, t + 1); }
    LGKM(4);                                  // prologue/p3 reads (8) done
    __builtin_amdgcn_sched_barrier(0);
    MFMA16(0, aF0, bF0);
    __builtin_amdgcn_s_barrier();

    // ---- p1: MFMA (A-hi, ks0); prefetch A-lo ks1 + B ks1; stage B(t+1) ----
    READ_A(aF0, 0, 1, bA);
    READ_B(bF1, 1, bB);
    if (more) { STAGE_B(0, nb, t + 1); STAGE_B(1, nb, t + 1); }
    LGKM(8);                                  // p0's 4 done
    __builtin_amdgcn_sched_barrier(0);
    MFMA16(1, aF1, bF0);
    __builtin_amdgcn_s_barrier();

    // ---- p2: MFMA (A-lo, ks1); prefetch A-hi ks1; drain own stage writes ----
    READ_A(aF1, 1, 1, bA);
    LGKM(4);                                  // p1's 8 done
    __builtin_amdgcn_sched_barrier(0);
    MFMA16(0, aF0, bF1);
    WAITV(0);                                 // own 8 stage-writes drained
    __builtin_amdgcn_s_barrier();             // => buf t+1 fully staged (all waves)

    // ---- p3: MFMA (A-hi, ks1); prefetch tile-t+1 p0 frags across boundary ----
    if (more) {
      READ_A(aF0, 0, 0, nbA);
      READ_B(bF0, 0, nbB);
      LGKM(8);                                // p2's 4 done
    } else {
      LGKM(0);
    }
    __builtin_amdgcn_sched_barrier(0);
    MFMA16(1, aF1, bF1);
    __builtin_amdgcn_s_barrier();
  }

  // epilogue: D row = (lane>>4)*4 + rr (M side), col = lane&15 (N side)
  const int r0 = (lane >> 4) * 4, cc = lane15;
#pragma unroll
  for (int mf = 0; mf < 8; ++mf) {
#pragma unroll
    for (int nf = 0; nf < 4; ++nf) {
#pragma unroll
      for (int rr = 0; rr < 4; ++rr) {
        const int row = tm + wm * 128 + mf * 16 + r0 + rr;
        if (row < NTREE) {
          const int col = tn + wn2 * 64 + nf * 16 + cc;
          C[(size_t)row * GNN + col] = f2bf(acc[mf][nf][rr]);
        }
      }
    }
  }
#undef MFMA16
#undef READ_A
#undef READ_B
#undef STAGE_A
#undef STAGE_B
}

// ---------------- K2: scores + masked softmax + dag_emb (bf16 out) --------
// E-gather loads hoisted to kernel top (unconditional, cf=0 for masked) so
// they overlap the score phase; single __syncthreads.
__global__ __launch_bounds__(512) void k_attn(const u16* __restrict__ PQ,
                                              const u16* __restrict__ Ebf,
                                              const float* __restrict__ b1,
                                              const float* __restrict__ w2,
                                              const float* __restrict__ b2,
                                              const float* __restrict__ masks,
                                              const int* __restrict__ leaves,
                                              const int* __restrict__ anc,
                                              u16* __restrict__ dag) {
  const int n = blockIdx.x;
  const int tid = threadIdx.x, lane = tid & 63, wv = tid >> 6;
  __shared__ float sc[8];
  __shared__ float m_s[8];

  // block-uniform ancestor ids (scalar loads)
  int anreg[8];
#pragma unroll
  for (int a = 0; a < 8; ++a) anreg[a] = anc[n * 8 + a];

  // hoisted unconditional E-gather: issues immediately, lands during scores
  uint32_t ew[8];
  if (tid < 384) {
    const int d = tid * 2;
#pragma unroll
    for (int a = 0; a < 8; ++a)
      ew[a] = *(const uint32_t*)(Ebf + (size_t)anreg[a] * HD + d);
  }

  // score phase: wave wv owns pair wv
  {
    const float mm = masks[n * 8 + wv];
    if (lane == 0) m_s[wv] = mm;
    if (mm == 0.f) {
      if (lane == 0) sc[wv] = VNEG;
    } else {
      const int l = leaves[n * 8 + wv];
      const u16* pr = PQ + (size_t)l * GNN;          // P (cols 0..767)
      const u16* qr = PQ + (size_t)anreg[wv] * GNN + HD;  // Q (cols 768..1535)
      u16x8  p1 = *(const u16x8*)(pr + lane * 8);
      u16x8  q1 = *(const u16x8*)(qr + lane * 8);
      ushort4 p2 = *(const ushort4*)(pr + 512 + lane * 4);
      ushort4 q2 = *(const ushort4*)(qr + 512 + lane * 4);
      const float4 bbA = *(const float4*)(b1 + lane * 8);
      const float4 bbB = *(const float4*)(b1 + lane * 8 + 4);
      const float4 bbC = *(const float4*)(b1 + 512 + lane * 4);
      const float4 wwA = *(const float4*)(w2 + lane * 8);
      const float4 wwB = *(const float4*)(w2 + lane * 8 + 4);
      const float4 wwC = *(const float4*)(w2 + 512 + lane * 4);
      float s = 0.f, v;
      v = fmaxf(bf2f(p1[0]) + bf2f(q1[0]) + bbA.x, 0.f); s += v * wwA.x;
      v = fmaxf(bf2f(p1[1]) + bf2f(q1[1]) + bbA.y, 0.f); s += v * wwA.y;
      v = fmaxf(bf2f(p1[2]) + bf2f(q1[2]) + bbA.z, 0.f); s += v * wwA.z;
      v = fmaxf(bf2f(p1[3]) + bf2f(q1[3]) + bbA.w, 0.f); s += v * wwA.w;
      v = fmaxf(bf2f(p1[4]) + bf2f(q1[4]) + bbB.x, 0.f); s += v * wwB.x;
      v = fmaxf(bf2f(p1[5]) + bf2f(q1[5]) + bbB.y, 0.f); s += v * wwB.y;
      v = fmaxf(bf2f(p1[6]) + bf2f(q1[6]) + bbB.z, 0.f); s += v * wwB.z;
      v = fmaxf(bf2f(p1[7]) + bf2f(q1[7]) + bbB.w, 0.f); s += v * wwB.w;
      v = fmaxf(bf2f(p2.x) + bf2f(q2.x) + bbC.x, 0.f);   s += v * wwC.x;
      v = fmaxf(bf2f(p2.y) + bf2f(q2.y) + bbC.y, 0.f);   s += v * wwC.y;
      v = fmaxf(bf2f(p2.z) + bf2f(q2.z) + bbC.z, 0.f);   s += v * wwC.z;
      v = fmaxf(bf2f(p2.w) + bf2f(q2.w) + bbC.w, 0.f);   s += v * wwC.w;
#pragma unroll
      for (int off = 32; off > 0; off >>= 1) s += __shfl_down(s, off);
      if (lane == 0) sc[wv] = s + b2[0];
    }
  }
  __syncthreads();

  if (tid < 384) {
    float mx = sc[0];
#pragma unroll
    for (int a = 1; a < 8; ++a) mx = fmaxf(mx, sc[a]);
    float ex[8], den = 0.f;
#pragma unroll
    for (int a = 0; a < 8; ++a) { ex[a] = expf(sc[a] - mx); den += ex[a]; }
    const float inv = 1.0f / den;
    float a0 = 0.f, a1 = 0.f;
#pragma unroll
    for (int a = 0; a < 8; ++a) {
      const float cfa = ex[a] * inv * m_s[a];
      a0 += cfa * bf2f((u16)(ew[a] & 0xffffu));
      a1 += cfa * bf2f((u16)(ew[a] >> 16));
    }
    const uint32_t packed = (uint32_t)f2bf(a0) | ((uint32_t)f2bf(a1) << 16);
    *(uint32_t*)(dag + (size_t)n * HD + tid * 2) = packed;
  }
}

// ---------------- K3: gather dict (bf16) + masked mean pooling ------------
// unconditional weighted gathers (idx clamped, weight zeroed) for MLP
__global__ __launch_bounds__(256) void k_pool(const u16* __restrict__ dag,
                                              const int* __restrict__ ids,
                                              const float* __restrict__ cm,
                                              float* __restrict__ pooled) {
  const int bv = blockIdx.x, tid = threadIdx.x;
  __shared__ int   ix_s[48];
  __shared__ float w_s[48];
  __shared__ float cm_s[48];
  if (tid < 48) {
    const int id = ids[bv * 48 + tid];
    const float cv = cm[bv * 48 + tid];
    cm_s[tid] = cv;
    ix_s[tid] = (id > 0) ? (id - 1) : 0;
    w_s[tid]  = (id > 0) ? cv : 0.f;
  }
  __syncthreads();
  float cnt = 0.f;
  for (int m = 0; m < 48; ++m) cnt += cm_s[m];
  const float scale = 1.0f / fmaxf(cnt, 1.0f);
  if (tid < 192) {
    float4 accv = make_float4(0.f, 0.f, 0.f, 0.f);
#pragma unroll 4
    for (int m = 0; m < 48; ++m) {
      const float w = w_s[m];
      ushort4 v = *(const ushort4*)(dag + (size_t)ix_s[m] * HD + tid * 4);
      accv.x += w * bf2f(v.x); accv.y += w * bf2f(v.y);
      accv.z += w * bf2f(v.z); accv.w += w * bf2f(v.w);
    }
    accv.x *= scale; accv.y *= scale; accv.z *= scale; accv.w *= scale;
    *(float4*)(pooled + (size_t)bv * HD + tid * 4) = accv;
  }
}

// ---------------- K4: out = pooled @ wc + bc (2D LDS mini-GEMM) -----------
__global__ __launch_bounds__(256) void k_out(const float* __restrict__ pooled,
                                             const float* __restrict__ wc,
                                             const float* __restrict__ bc,
                                             float* __restrict__ out) {
  const int rb = blockIdx.x >> 3, cb = blockIdx.x & 7;
  const int tid = threadIdx.x;
  const int ty = tid >> 4, tx = tid & 15;
  __shared__ float pl[64][33];
  __shared__ float wcs[32][64];
  float acc[4][4];
#pragma unroll
  for (int i = 0; i < 4; ++i)
#pragma unroll
    for (int j = 0; j < 4; ++j) acc[i][j] = 0.f;

  for (int kt = 0; kt < HD / 32; ++kt) {
    __syncthreads();
#pragma unroll
    for (int u = 0; u < 2; ++u) {
      const int i = u * 256 + tid;           // 0..511
      const int r = i >> 3, kq = (i & 7) * 4;
      float4 v = *(const float4*)(pooled + (size_t)(rb * 64 + r) * HD + kt * 32 + kq);
      pl[r][kq] = v.x; pl[r][kq + 1] = v.y; pl[r][kq + 2] = v.z; pl[r][kq + 3] = v.w;
    }
#pragma unroll
    for (int u = 0; u < 2; ++u) {
      const int i = u * 256 + tid;
      const int k = i >> 4, cq = (i & 15) * 4;
      *(float4*)&wcs[k][cq] =
          *(const float4*)(wc + (size_t)(kt * 32 + k) * OUTD + cb * 64 + cq);
    }
    __syncthreads();
#pragma unroll 8
    for (int k = 0; k < 32; ++k) {
      const float a0 = pl[ty * 4 + 0][k], a1 = pl[ty * 4 + 1][k];
      const float a2 = pl[ty * 4 + 2][k], a3 = pl[ty * 4 + 3][k];
      const float4 b = *(const float4*)&wcs[k][tx * 4];
      acc[0][0] += a0 * b.x; acc[0][1] += a0 * b.y; acc[0][2] += a0 * b.z; acc[0][3] += a0 * b.w;
      acc[1][0] += a1 * b.x; acc[1][1] += a1 * b.y; acc[1][2] += a1 * b.z; acc[1][3] += a1 * b.w;
      acc[2][0] += a2 * b.x; acc[2][1] += a2 * b.y; acc[2][2] += a2 * b.z; acc[2][3] += a2 * b.w;
      acc[3][0] += a3 * b.x; acc[3][1] += a3 * b.y; acc[3][2] += a3 * b.z; acc[3][3] += a3 * b.w;
    }
  }
#pragma unroll
  for (int i = 0; i < 4; ++i) {
#pragma unroll
    for (int j = 0; j < 4; ++j) {
      const int row = rb * 64 + ty * 4 + i;
      const int col = cb * 64 + tx * 4 + j;
      out[(size_t)row * OUTD + col] = acc[i][j] + bc[col];
    }
  }
}

extern "C" void kernel_launch(void* const* d_in, const int* in_sizes, int n_in,
                              void* d_out, int out_size, void* d_ws, size_t ws_size,
                              hipStream_t stream) {
  const float* E     = (const float*)d_in[0];
  const float* w1    = (const float*)d_in[1];
  const float* b1    = (const float*)d_in[2];
  const float* w2    = (const float*)d_in[3];
  const float* b2    = (const float*)d_in[4];
  const float* wc    = (const float*)d_in[5];
  const float* bc    = (const float*)d_in[6];
  const float* masks = (const float*)d_in[7];
  const float* cm    = (const float*)d_in[8];
  const int*   leaves = (const int*)d_in[9];
  const int*   anc    = (const int*)d_in[10];
  const int*   ids    = (const int*)d_in[11];
  float* out = (float*)d_out;

  if (n_in < 12) return;
  if (in_sizes[0] != NTREE * HD) return;
  if (out_size != NBV * OUTD) return;

  char* ws = (char*)d_ws;
  const size_t szEbf = (size_t)NTREE * HD * 2;
  const size_t szBt  = (size_t)GNN * HD * 2;
  const size_t szPQ  = (size_t)NTREE * GNN * 2;
  const size_t szDag = (size_t)NCODES * HD * 2;
  const size_t szPl  = (size_t)NBV * HD * 4;
  if (ws_size < szEbf + szBt + szPQ + szDag + szPl) return;  // ~196 MB

  u16*   Ebf    = (u16*)ws;            ws += szEbf;
  u16*   Bt     = (u16*)ws;            ws += szBt;
  u16*   PQ     = (u16*)ws;            ws += szPQ;
  u16*   dag    = (u16*)ws;            ws += szDag;
  float* pooled = (float*)ws;          ws += szPl;

  const int nPrep = NBLK_CONV + (GNN * HD + 255) / 256;
  k_prep<<<nPrep, 256, 0, stream>>>(E, Ebf, w1, Bt);
  k_gemm<<<GRID, 512, 0, stream>>>(Ebf, Bt, PQ);
  k_attn<<<NCODES, 512, 0, stream>>>(PQ, Ebf, b1, w2, b2, masks, leaves, anc, dag);
  k_pool<<<NBV, 256, 0, stream>>>(dag, ids, cm, pooled);
  k_out<<<64, 256, 0, stream>>>(pooled, wc, bc, out);
}